// Round 9
// baseline (71758.527 us; speedup 1.0000x reference)
//
#include <hip/hip_runtime.h>
#include <hip/hip_cooperative_groups.h>

namespace cg = cooperative_groups;

// ManyToOne GRU: N=256, L=512, I=512, H=1024.
// Round 8: persistent cooperative kernel. Round-7 structure, but the custom
// spin barrier (suspected 65 GB write-storm source) is replaced by the
// round-2-proven {__threadfence; grid.sync(); __threadfence} protocol, and
// register pressure is reduced (per-j pipelined A-loads, no a[4][4] block).
//  - B-hi h-part in LDS (96 KB, staged once); B-lo + x-part B from L2/L3.
//  - bf16 h exchange via plain loads/stores; f32 h blend state in registers.
//  - x-part GEMM of step t+1 (immutable inputs only) runs before grid.sync.
//  - Numerics = rounds 4-7: 2-limb bf16 B, bf16-RTN A, f32 h blend.

typedef unsigned short u16;
typedef unsigned int   u32;
typedef __attribute__((ext_vector_type(4))) float f32x4;
typedef __attribute__((ext_vector_type(8))) short s16x8;

constexpr int NB   = 256;
constexpr int LSEQ = 512;
constexpr int ISZ  = 512;
constexpr int HSZ  = 1024;

constexpr int TILE_U16  = 48 * 1536;       // u16 per 16-col tile per plane
constexpr int TILEBYTES = TILE_U16 * 2;    // 147456
constexpr int BH_LDS    = 96 * 1024;       // h-part hi panels (kb 16..47)
constexpr int LDS_TOTAL = BH_LDS + 32768;  // + 4 scratch slots * 8 KB = 131072

__device__ __forceinline__ u16 bf16_trunc(float f) {
    union { float f; u32 u; } v; v.f = f; return (u16)(v.u >> 16);
}
__device__ __forceinline__ float bf16_up(u16 h) {
    union { float f; u32 u; } v; v.u = ((u32)h) << 16; return v.f;
}
__device__ __forceinline__ u16 bf16_rtn(float f) {
    union { float f; u32 u; } v; v.f = f;
    u32 u = v.u; u += 0x7FFFu + ((u >> 16) & 1u);
    return (u16)(u >> 16);
}

#define GLL16(g, l) __builtin_amdgcn_global_load_lds(                          \
    (const __attribute__((address_space(1))) u32*)(g),                         \
    (__attribute__((address_space(3))) u32*)(l), 16, 0, 0)

#define MF(a, b, c) __builtin_amdgcn_mfma_f32_16x16x32_bf16(a, b, c, 0, 0, 0)

// ---------------------------------------------------------------- prep ----
// Single-plane panel layout per tile c (u16 idx): kb*1536 + p*512 + kg*128 +
// col*8 + e.  kb<16: x-part (W_ih), kb>=16: h-part (W_hh). p: 0=r, 1=z, 2=n.
__global__ __launch_bounds__(256) void prep_kernel(
    const float* __restrict__ W_ih, const float* __restrict__ W_hh,
    const float* __restrict__ b_ih, const float* __restrict__ b_hh,
    const float* __restrict__ W_out,
    u16* __restrict__ Bhi, u16* __restrict__ Blo,
    float* __restrict__ Wt, float4* __restrict__ bias4)
{
    int idx = blockIdx.x * 256 + threadIdx.x;
    if (idx < 64 * TILE_U16) {
        int c   = idx / TILE_U16;
        int r1  = idx % TILE_U16;
        int kb  = r1 / 1536;
        int r2  = r1 % 1536;
        int p   = r2 / 512;
        int r3  = r2 % 512;
        int kg  = r3 >> 7;
        int col = (r3 >> 3) & 15;
        int e   = r3 & 7;
        int kloc = kg * 8 + e;
        int gcol = c * 16 + col;
        float w;
        if (kb < 16) w = W_ih[(p * HSZ + gcol) * ISZ + kb * 32 + kloc];
        else         w = W_hh[(p * HSZ + gcol) * HSZ + (kb - 16) * 32 + kloc];
        u16 hi = bf16_trunc(w);
        Bhi[idx] = hi;
        Blo[idx] = bf16_trunc(w - bf16_up(hi));
    }
    if (idx < HSZ * ISZ) {           // Wt[k][i] = W_out[i][k]
        int i = idx % ISZ, k = idx / ISZ;
        Wt[idx] = W_out[i * HSZ + k];
    }
    if (idx < HSZ) {
        bias4[idx] = make_float4(b_ih[idx] + b_hh[idx],
                                 b_ih[HSZ + idx] + b_hh[HSZ + idx],
                                 b_ih[2 * HSZ + idx],
                                 b_hh[2 * HSZ + idx]);
    }
}

// ---------------------------------------------------------------- init ----
__global__ __launch_bounds__(256) void init_kernel(
    const float* __restrict__ h_in,
    float* __restrict__ hf, u16* __restrict__ hb0)
{
    int idx = blockIdx.x * 256 + threadIdx.x;    // NB*HSZ threads
    float v = h_in[idx];
    hf[idx]  = v;
    hb0[idx] = bf16_rtn(v);
}

// ---------------------------------------------------------- persistent ----
__global__ __launch_bounds__(512, 1) void gru_persistent(
    const float* __restrict__ x,
    const u16* __restrict__ Bhi, const u16* __restrict__ Blo,
    const float4* __restrict__ bias4,
    float* __restrict__ hf, u16* __restrict__ hb0, u16* __restrict__ hb1)
{
    extern __shared__ char lds[];
    float* scr = (float*)(lds + BH_LDS);     // 4 slots * 2048 floats
    cg::grid_group grid = cg::this_grid();

    const int tid  = threadIdx.x;
    const int lane = tid & 63;
    const int wv   = tid >> 6;               // 0..7
    const int lr   = lane & 15;
    const int kg   = lane >> 4;
    const int raw  = blockIdx.x;
    const int c    = ((raw & 7) << 3) | ((raw >> 3) & 7);  // XCD raw&7 owns 8 tiles
    const int m    = raw >> 6;
    const int fro  = kg * 128 + lr * 8;      // u16 offset within 1KB panel
    const int frob = fro * 2;                // byte offset

    const u16* bhit = Bhi + (size_t)c * TILE_U16;
    const u16* blot = Blo + (size_t)c * TILE_U16;

    // ---- stage B-hi h-part (kb 16..47) into LDS once: 96 segs of 1KB ----
    {
        const char* src = (const char*)bhit + 16 * 3072;
        #pragma unroll
        for (int i = 0; i < 12; ++i) {
            int seg = i * 8 + wv;
            GLL16(src + seg * 1024 + lane * 16, lds + seg * 1024);
        }
    }

    const float4 b4 = bias4[c * 16 + lr];

    // ---- h f32 blend state in registers (epilogue waves 0/1 own rt pairs)
    float hreg[2][4];
    const int rt0 = (wv == 0) ? 0 : 2;       // wv0 -> rt{0,1}, wv1 -> rt{2,3}
    if (wv < 2) {
        const int j = c * 16 + lr;
        #pragma unroll
        for (int rr = 0; rr < 2; ++rr)
            #pragma unroll
            for (int i = 0; i < 4; ++i) {
                const int row = m * 64 + (rt0 + rr) * 16 + kg * 4 + i;
                hreg[rr][i] = hf[row * HSZ + j];
            }
    }

    f32x4 acc[4][4];   // [rt][set]: 0=r, 1=z, 2=n_x, 3=n_h
    #pragma unroll
    for (int rt = 0; rt < 4; ++rt)
        #pragma unroll
        for (int s = 0; s < 4; ++s) acc[rt][s] = (f32x4){0.f, 0.f, 0.f, 0.f};

    // x-part partials for time tt (reads only immutable x/B -> race-free)
    auto xpart = [&](int tt) {
        #pragma unroll
        for (int jx = 0; jx < 2; ++jx) {
            const int kb = wv * 2 + jx;
            s16x8 xh[3], xl[3];
            #pragma unroll
            for (int p = 0; p < 3; ++p) {
                xh[p] = *(const s16x8*)(bhit + kb * 1536 + p * 512 + fro);
                xl[p] = *(const s16x8*)(blot + kb * 1536 + p * 512 + fro);
            }
            #pragma unroll
            for (int rt = 0; rt < 4; ++rt) {
                const int row = m * 64 + rt * 16 + lr;
                const float* xp = x + ((size_t)row * LSEQ + tt) * ISZ + kb * 32 + kg * 8;
                f32x4 a0 = *(const f32x4*)xp;
                f32x4 a1 = *(const f32x4*)(xp + 4);
                s16x8 a;
                #pragma unroll
                for (int e = 0; e < 4; ++e) {
                    a[e]     = (short)bf16_rtn(a0[e]);
                    a[e + 4] = (short)bf16_rtn(a1[e]);
                }
                acc[rt][0] = MF(a, xh[0], acc[rt][0]);
                acc[rt][0] = MF(a, xl[0], acc[rt][0]);
                acc[rt][1] = MF(a, xh[1], acc[rt][1]);
                acc[rt][1] = MF(a, xl[1], acc[rt][1]);
                acc[rt][2] = MF(a, xh[2], acc[rt][2]);
                acc[rt][2] = MF(a, xl[2], acc[rt][2]);
            }
        }
    };
    __syncthreads();                         // B-hi staged
    xpart(0);

    for (int t = 0; t < LSEQ; ++t) {
        const u16* hbc = (t & 1) ? hb1 : hb0;
        u16*       hbn = (t & 1) ? hb0 : hb1;

        // ---- h-part: per-j A-loads (1-deep pipeline) + MFMA ----
        s16x8 aj[4], an[4];
        #pragma unroll
        for (int rt = 0; rt < 4; ++rt) {
            const int row = m * 64 + rt * 16 + lr;
            aj[rt] = *(const s16x8*)(hbc + (size_t)row * HSZ + (wv * 4) * 32 + kg * 8);
        }
        #pragma unroll
        for (int j = 0; j < 4; ++j) {
            if (j + 1 < 4) {
                const int khoff = (wv * 4 + j + 1) * 32;
                #pragma unroll
                for (int rt = 0; rt < 4; ++rt) {
                    const int row = m * 64 + rt * 16 + lr;
                    an[rt] = *(const s16x8*)(hbc + (size_t)row * HSZ + khoff + kg * 8);
                }
            }
            const char* lp = lds + (wv * 4 + j) * 3072 + frob;
            s16x8 bh0 = *(const s16x8*)lp;
            s16x8 bh1 = *(const s16x8*)(lp + 1024);
            s16x8 bh2 = *(const s16x8*)(lp + 2048);
            const u16* gp = blot + (size_t)(16 + wv * 4 + j) * 1536 + fro;
            s16x8 bl0 = *(const s16x8*)gp;
            s16x8 bl1 = *(const s16x8*)(gp + 512);
            s16x8 bl2 = *(const s16x8*)(gp + 1024);
            #pragma unroll
            for (int rt = 0; rt < 4; ++rt) {
                acc[rt][0] = MF(aj[rt], bh0, acc[rt][0]);
                acc[rt][0] = MF(aj[rt], bl0, acc[rt][0]);
                acc[rt][1] = MF(aj[rt], bh1, acc[rt][1]);
                acc[rt][1] = MF(aj[rt], bl1, acc[rt][1]);
                acc[rt][3] = MF(aj[rt], bh2, acc[rt][3]);
                acc[rt][3] = MF(aj[rt], bl2, acc[rt][3]);
            }
            if (j + 1 < 4) {
                #pragma unroll
                for (int rt = 0; rt < 4; ++rt) aj[rt] = an[rt];
            }
        }

        // ---- 8-way K reduction (2-phase R1, then R2, R3) ----
        __syncthreads();                                   // b1
        #pragma unroll
        for (int ph = 0; ph < 2; ++ph) {                   // R1: sets {0,1},{2,3}
            if (wv >= 4) {
                float* sp = scr + (wv - 4) * 2048 + lane * 4;
                #pragma unroll
                for (int rt = 0; rt < 4; ++rt)
                    #pragma unroll
                    for (int q = 0; q < 2; ++q)
                        *(f32x4*)(sp + (rt * 2 + q) * 256) = acc[rt][ph * 2 + q];
            }
            __syncthreads();                               // b2 / b4
            if (wv < 4) {
                const float* sp = scr + wv * 2048 + lane * 4;
                #pragma unroll
                for (int rt = 0; rt < 4; ++rt)
                    #pragma unroll
                    for (int q = 0; q < 2; ++q)
                        acc[rt][ph * 2 + q] += *(const f32x4*)(sp + (rt * 2 + q) * 256);
            }
            __syncthreads();                               // b3 / b5
        }
        if (wv == 2 || wv == 3) {                          // R2 write
            float* sp0 = scr + (wv - 2) * 2 * 2048 + lane * 4;
            #pragma unroll
            for (int rt = 0; rt < 4; ++rt)
                #pragma unroll
                for (int s = 0; s < 4; ++s)
                    *(f32x4*)(sp0 + (s >> 1) * 2048 + (rt * 2 + (s & 1)) * 256) = acc[rt][s];
        }
        __syncthreads();                                   // b6
        if (wv < 2) {                                      // R2 add
            const float* sp0 = scr + wv * 2 * 2048 + lane * 4;
            #pragma unroll
            for (int rt = 0; rt < 4; ++rt)
                #pragma unroll
                for (int s = 0; s < 4; ++s)
                    acc[rt][s] += *(const f32x4*)(sp0 + (s >> 1) * 2048 + (rt * 2 + (s & 1)) * 256);
        }
        __syncthreads();                                   // b7
        if (wv == 0) {                                     // R3 write rt{2,3} -> slot 0
            float* sp = scr + lane * 4;
            #pragma unroll
            for (int rr = 0; rr < 2; ++rr)
                #pragma unroll
                for (int s = 0; s < 4; ++s)
                    *(f32x4*)(sp + (rr * 4 + s) * 256) = acc[2 + rr][s];
        } else if (wv == 1) {                              // rt{0,1} -> slot 1
            float* sp = scr + 2048 + lane * 4;
            #pragma unroll
            for (int rr = 0; rr < 2; ++rr)
                #pragma unroll
                for (int s = 0; s < 4; ++s)
                    *(f32x4*)(sp + (rr * 4 + s) * 256) = acc[rr][s];
        }
        __syncthreads();                                   // b8
        if (wv < 2) {                                      // R3 add + epilogue
            const float* sp = scr + (1 - wv) * 2048 + lane * 4;
            #pragma unroll
            for (int rr = 0; rr < 2; ++rr)
                #pragma unroll
                for (int s = 0; s < 4; ++s)
                    acc[rt0 + rr][s] += *(const f32x4*)(sp + (rr * 4 + s) * 256);
            const int j = c * 16 + lr;
            #pragma unroll
            for (int rr = 0; rr < 2; ++rr) {
                const int rt = rt0 + rr;
                #pragma unroll
                for (int i = 0; i < 4; ++i) {
                    const int row = m * 64 + rt * 16 + kg * 4 + i;
                    float r_ = 1.f / (1.f + __expf(-(acc[rt][0][i] + b4.x)));
                    float z_ = 1.f / (1.f + __expf(-(acc[rt][1][i] + b4.y)));
                    float pre = (acc[rt][2][i] + b4.z) + r_ * (acc[rt][3][i] + b4.w);
                    float e2 = __expf(2.f * pre);
                    float ng = 1.f - 2.f / (e2 + 1.f);
                    float ho = hreg[rr][i];
                    float hn = (1.f - z_) * ng + z_ * ho;
                    hreg[rr][i] = hn;
                    hbn[row * HSZ + j] = bf16_rtn(hn);     // plain store
                    if (t == LSEQ - 1) hf[row * HSZ + j] = hn;
                }
            }
        }
        __syncthreads();                                   // b9: stores issued

        if (t + 1 < LSEQ) {
            __threadfence();                               // release: L2 -> L3
            // ---- pre-barrier slack: x-part partials for step t+1 ----
            #pragma unroll
            for (int rt = 0; rt < 4; ++rt)
                #pragma unroll
                for (int s = 0; s < 4; ++s) acc[rt][s] = (f32x4){0.f, 0.f, 0.f, 0.f};
            xpart(t + 1);
            grid.sync();                                   // proven-clean barrier
            __threadfence();                               // acquire: inv stale L2
        }
    }
}

// ---------------------------------------------------------------- head ----
__global__ __launch_bounds__(256) void head_kernel(
    const float* __restrict__ hfin, const float* __restrict__ Wt,
    const float* __restrict__ b_out, float* __restrict__ out)
{
    __shared__ float hrow[HSZ];
    const int n = blockIdx.x;
    const int tid = threadIdx.x;
    for (int k = tid; k < HSZ; k += 256) {
        float v = hfin[n * HSZ + k];
        hrow[k] = v;
        out[NB * ISZ + n * HSZ + k] = v;   // h_final output
    }
    __syncthreads();
    for (int j = tid; j < ISZ; j += 256) {
        float acc = b_out[j];
        #pragma unroll 8
        for (int k = 0; k < HSZ; ++k)
            acc = fmaf(hrow[k], Wt[k * ISZ + j], acc);
        out[n * ISZ + j] = acc;
    }
}

// -------------------------------------------------------------- launch ----
extern "C" void kernel_launch(void* const* d_in, const int* in_sizes, int n_in,
                              void* d_out, int out_size, void* d_ws, size_t ws_size,
                              hipStream_t stream) {
    (void)in_sizes; (void)n_in; (void)out_size; (void)ws_size;
    const float* x     = (const float*)d_in[0];
    const float* h_in  = (const float*)d_in[1];
    const float* W_ih  = (const float*)d_in[2];
    const float* b_ih  = (const float*)d_in[3];
    const float* W_hh  = (const float*)d_in[4];
    const float* b_hh  = (const float*)d_in[5];
    const float* W_out = (const float*)d_in[6];
    const float* b_out = (const float*)d_in[7];
    float* out = (float*)d_out;

    char* ws = (char*)d_ws;
    size_t o = 0;
    u16*    Bhi   = (u16*)(ws + o);    o += (size_t)64 * TILEBYTES;   // 9,437,184
    u16*    Blo   = (u16*)(ws + o);    o += (size_t)64 * TILEBYTES;   // 9,437,184
    float*  Wt    = (float*)(ws + o);  o += (size_t)HSZ * ISZ * 4;    // 2,097,152
    float4* bias4 = (float4*)(ws + o); o += (size_t)HSZ * 16;         //    16,384
    float*  hf    = (float*)(ws + o);  o += (size_t)NB * HSZ * 4;     // 1,048,576
    u16*    hb0   = (u16*)(ws + o);    o += (size_t)NB * HSZ * 2;     //   524,288
    u16*    hb1   = (u16*)(ws + o);    o += (size_t)NB * HSZ * 2;     //   524,288
    // total ~23.1 MB

    prep_kernel<<<(64 * TILE_U16) / 256, 256, 0, stream>>>(
        W_ih, W_hh, b_ih, b_hh, W_out, Bhi, Blo, Wt, bias4);
    init_kernel<<<(NB * HSZ) / 256, 256, 0, stream>>>(h_in, hf, hb0);

    {
        const float* xp = x;
        const u16* bhip = Bhi;
        const u16* blop = Blo;
        const float4* b4p = bias4;
        float* hfp = hf;
        u16* h0p = hb0;
        u16* h1p = hb1;
        void* args[] = {(void*)&xp, (void*)&bhip, (void*)&blop, (void*)&b4p,
                        (void*)&hfp, (void*)&h0p, (void*)&h1p};
        hipLaunchCooperativeKernel((void*)gru_persistent, dim3(256), dim3(512),
                                   args, LDS_TOTAL, stream);
    }

    head_kernel<<<NB, 256, 0, stream>>>(hf, Wt, b_out, out);
}

// Round 10
// 7018.919 us; speedup vs baseline: 10.2236x; 10.2236x over previous
//
#include <hip/hip_runtime.h>

// ManyToOne GRU: N=256, L=512, I=512, H=1024.
// Round 9: per-step kernel (round-4 family, best=6.75ms), de-serialized:
//  - NO LDS staging of B: weights read straight from L2/L3 (c-pinned XCD
//    swizzle keeps the 294KB tile L2-shared by its 4 m-WGs). Removes the
//    one-shot GLL16 chain + its barrier.
//  - 512 threads (8 waves, 2/SIMD, 256-VGPR budget -> no spills), 8-way
//    K-split (6 kb/wave), 6-barrier LDS reduction (64KB), 1-wave epilogue.
//  - f32 h state updated in-place in ws (exclusive per-WG ownership).
//  - Numerics = round 4: 2-limb bf16 B, single-plane bf16-RTN A, f32 blend.

typedef unsigned short u16;
typedef unsigned int   u32;
typedef __attribute__((ext_vector_type(4))) float f32x4;
typedef __attribute__((ext_vector_type(8))) short s16x8;

constexpr int NB   = 256;
constexpr int LSEQ = 512;
constexpr int ISZ  = 512;
constexpr int HSZ  = 1024;

constexpr int TILE_U16  = 48 * 1536;       // u16 per 16-col tile per plane
constexpr int TILEBYTES = TILE_U16 * 2;    // 147456
constexpr int LDS_BYTES = 65536;           // 4 reduction slots * 16 KB

__device__ __forceinline__ u16 bf16_trunc(float f) {
    union { float f; u32 u; } v; v.f = f; return (u16)(v.u >> 16);
}
__device__ __forceinline__ float bf16_up(u16 h) {
    union { float f; u32 u; } v; v.u = ((u32)h) << 16; return v.f;
}
__device__ __forceinline__ u16 bf16_rtn(float f) {
    union { float f; u32 u; } v; v.f = f;
    u32 u = v.u; u += 0x7FFFu + ((u >> 16) & 1u);
    return (u16)(u >> 16);
}

#define MF(a, b, c) __builtin_amdgcn_mfma_f32_16x16x32_bf16(a, b, c, 0, 0, 0)

// ---------------------------------------------------------------- prep ----
// Single-plane panel layout per tile c (u16 idx): kb*1536 + p*512 + kg*128 +
// col*8 + e.  kb<16: x-part (W_ih), kb>=16: h-part (W_hh). p: 0=r, 1=z, 2=n.
__global__ __launch_bounds__(256) void prep_kernel(
    const float* __restrict__ W_ih, const float* __restrict__ W_hh,
    const float* __restrict__ b_ih, const float* __restrict__ b_hh,
    const float* __restrict__ W_out,
    u16* __restrict__ Bhi, u16* __restrict__ Blo,
    float* __restrict__ Wt, float4* __restrict__ bias4)
{
    int idx = blockIdx.x * 256 + threadIdx.x;
    if (idx < 64 * TILE_U16) {
        int c   = idx / TILE_U16;
        int r1  = idx % TILE_U16;
        int kb  = r1 / 1536;
        int r2  = r1 % 1536;
        int p   = r2 / 512;
        int r3  = r2 % 512;
        int kg  = r3 >> 7;
        int col = (r3 >> 3) & 15;
        int e   = r3 & 7;
        int kloc = kg * 8 + e;
        int gcol = c * 16 + col;
        float w;
        if (kb < 16) w = W_ih[(p * HSZ + gcol) * ISZ + kb * 32 + kloc];
        else         w = W_hh[(p * HSZ + gcol) * HSZ + (kb - 16) * 32 + kloc];
        u16 hi = bf16_trunc(w);
        Bhi[idx] = hi;
        Blo[idx] = bf16_trunc(w - bf16_up(hi));
    }
    if (idx < HSZ * ISZ) {           // Wt[k][i] = W_out[i][k]
        int i = idx % ISZ, k = idx / ISZ;
        Wt[idx] = W_out[i * HSZ + k];
    }
    if (idx < HSZ) {
        bias4[idx] = make_float4(b_ih[idx] + b_hh[idx],
                                 b_ih[HSZ + idx] + b_hh[HSZ + idx],
                                 b_ih[2 * HSZ + idx],
                                 b_hh[2 * HSZ + idx]);
    }
}

// ---------------------------------------------------------------- init ----
__global__ __launch_bounds__(256) void init_kernel(
    const float* __restrict__ x, const float* __restrict__ h_in,
    u16* __restrict__ xb0, float* __restrict__ hf0, u16* __restrict__ hb0)
{
    int idx = blockIdx.x * 256 + threadIdx.x;    // 131072 threads
    {
        int n = idx >> 9, k = idx & (ISZ - 1);
        xb0[idx] = bf16_rtn(x[(size_t)n * (LSEQ * ISZ) + k]);
    }
    #pragma unroll
    for (int q = 0; q < 2; ++q) {
        int e = idx * 2 + q;
        float v = h_in[e];
        hf0[e] = v;
        hb0[e] = bf16_rtn(v);
    }
}

// ---------------------------------------------------------------- step ----
__global__ __launch_bounds__(512, 1) void gru_step(
    const float* __restrict__ x, int t,
    const u16* __restrict__ Bhi, const u16* __restrict__ Blo,
    const float4* __restrict__ bias4,
    const u16* __restrict__ xb, u16* __restrict__ xb_n,
    float* __restrict__ hf,
    const u16* __restrict__ hb, u16* __restrict__ hb_n)
{
    extern __shared__ float scr[];           // 4 slots * 4096 floats

    const int tid  = threadIdx.x;
    const int lane = tid & 63;
    const int wv   = tid >> 6;               // 0..7
    const int lr   = lane & 15;
    const int kg   = lane >> 4;
    const int raw  = blockIdx.x;             // 0..255
    const int c    = ((raw & 7) << 3) | ((raw >> 3) & 7);  // XCD raw&7: 8 tiles
    const int m    = raw >> 6;
    const int fro  = kg * 128 + lr * 8;      // u16 offset within 1KB panel

    // ---- x_{t+1} conversion: 1 elem/thread (256 WG x 512 = NB*ISZ) ----
    if (t + 1 < LSEQ) {
        int e = raw * 512 + tid;
        int n = e >> 9, k = e & (ISZ - 1);
        xb_n[e] = bf16_rtn(x[(size_t)n * (LSEQ * ISZ) + (size_t)(t + 1) * ISZ + k]);
    }

    const u16* bhit = Bhi + (size_t)c * TILE_U16;
    const u16* blot = Blo + (size_t)c * TILE_U16;

    f32x4 acc[4][4];   // [rt][set]: 0=r, 1=z, 2=n_x, 3=n_h
    #pragma unroll
    for (int rt = 0; rt < 4; ++rt)
        #pragma unroll
        for (int s = 0; s < 4; ++s) acc[rt][s] = (f32x4){0.f, 0.f, 0.f, 0.f};

    // ---- main: wave wv owns kb = 6wv .. 6wv+5, straight from L2 ----
    #pragma unroll 2
    for (int j = 0; j < 6; ++j) {
        const int kb = wv * 6 + j;
        const u16* gh = bhit + kb * 1536 + fro;
        const u16* gl = blot + kb * 1536 + fro;
        s16x8 bh0 = *(const s16x8*)gh;
        s16x8 bh1 = *(const s16x8*)(gh + 512);
        s16x8 bh2 = *(const s16x8*)(gh + 1024);
        s16x8 bl0 = *(const s16x8*)gl;
        s16x8 bl1 = *(const s16x8*)(gl + 512);
        s16x8 bl2 = *(const s16x8*)(gl + 1024);
        const bool isx = (kb < 16);          // wave-uniform
        s16x8 a[4];
        if (isx) {
            #pragma unroll
            for (int rt = 0; rt < 4; ++rt) {
                const int row = m * 64 + rt * 16 + lr;
                a[rt] = *(const s16x8*)(xb + row * ISZ + kb * 32 + kg * 8);
            }
        } else {
            #pragma unroll
            for (int rt = 0; rt < 4; ++rt) {
                const int row = m * 64 + rt * 16 + lr;
                a[rt] = *(const s16x8*)(hb + row * HSZ + (kb - 16) * 32 + kg * 8);
            }
        }
        #pragma unroll
        for (int rt = 0; rt < 4; ++rt) {
            acc[rt][0] = MF(a[rt], bh0, acc[rt][0]);
            acc[rt][0] = MF(a[rt], bl0, acc[rt][0]);
            acc[rt][1] = MF(a[rt], bh1, acc[rt][1]);
            acc[rt][1] = MF(a[rt], bl1, acc[rt][1]);
        }
        if (isx) {
            #pragma unroll
            for (int rt = 0; rt < 4; ++rt) {
                acc[rt][2] = MF(a[rt], bh2, acc[rt][2]);
                acc[rt][2] = MF(a[rt], bl2, acc[rt][2]);
            }
        } else {
            #pragma unroll
            for (int rt = 0; rt < 4; ++rt) {
                acc[rt][3] = MF(a[rt], bh2, acc[rt][3]);
                acc[rt][3] = MF(a[rt], bl2, acc[rt][3]);
            }
        }
    }

    // ---- 8-way reduction tree: slot sl at scr+sl*4096; entry
    //      (rt*4+set)*256 + lane*4 ----
    if (wv >= 4) {                                         // R1 write
        float* sp = scr + (wv - 4) * 4096 + lane * 4;
        #pragma unroll
        for (int rt = 0; rt < 4; ++rt)
            #pragma unroll
            for (int s = 0; s < 4; ++s)
                *(f32x4*)(sp + (rt * 4 + s) * 256) = acc[rt][s];
    }
    __syncthreads();                                       // b1
    if (wv < 4) {                                          // R1 add
        const float* sp = scr + wv * 4096 + lane * 4;
        #pragma unroll
        for (int rt = 0; rt < 4; ++rt)
            #pragma unroll
            for (int s = 0; s < 4; ++s)
                acc[rt][s] += *(const f32x4*)(sp + (rt * 4 + s) * 256);
    }
    __syncthreads();                                       // b2
    if (wv == 2 || wv == 3) {                              // R2 write
        float* sp = scr + (wv - 2) * 4096 + lane * 4;
        #pragma unroll
        for (int rt = 0; rt < 4; ++rt)
            #pragma unroll
            for (int s = 0; s < 4; ++s)
                *(f32x4*)(sp + (rt * 4 + s) * 256) = acc[rt][s];
    }
    __syncthreads();                                       // b3
    if (wv < 2) {                                          // R2 add
        const float* sp = scr + wv * 4096 + lane * 4;
        #pragma unroll
        for (int rt = 0; rt < 4; ++rt)
            #pragma unroll
            for (int s = 0; s < 4; ++s)
                acc[rt][s] += *(const f32x4*)(sp + (rt * 4 + s) * 256);
    }
    __syncthreads();                                       // b4
    if (wv == 1) {                                         // R3 write
        float* sp = scr + lane * 4;
        #pragma unroll
        for (int rt = 0; rt < 4; ++rt)
            #pragma unroll
            for (int s = 0; s < 4; ++s)
                *(f32x4*)(sp + (rt * 4 + s) * 256) = acc[rt][s];
    }
    __syncthreads();                                       // b5
    if (wv == 0) {                                         // R3 add + epilogue
        const float* sp = scr + lane * 4;
        #pragma unroll
        for (int rt = 0; rt < 4; ++rt)
            #pragma unroll
            for (int s = 0; s < 4; ++s)
                acc[rt][s] += *(const f32x4*)(sp + (rt * 4 + s) * 256);
        const int j = c * 16 + lr;
        const float4 b4 = bias4[j];
        #pragma unroll
        for (int rt = 0; rt < 4; ++rt) {
            #pragma unroll
            for (int i = 0; i < 4; ++i) {
                const int row = m * 64 + rt * 16 + kg * 4 + i;
                float r_ = 1.f / (1.f + __expf(-(acc[rt][0][i] + b4.x)));
                float z_ = 1.f / (1.f + __expf(-(acc[rt][1][i] + b4.y)));
                float pre = (acc[rt][2][i] + b4.z) + r_ * (acc[rt][3][i] + b4.w);
                float e2 = __expf(2.f * pre);
                float ng = 1.f - 2.f / (e2 + 1.f);
                float ho = hf[row * HSZ + j];
                float hn = (1.f - z_) * ng + z_ * ho;
                hf[row * HSZ + j] = hn;                    // in-place f32 state
                hb_n[row * HSZ + j] = bf16_rtn(hn);
            }
        }
    }
}

// ---------------------------------------------------------------- head ----
__global__ __launch_bounds__(256) void head_kernel(
    const float* __restrict__ hfin, const float* __restrict__ Wt,
    const float* __restrict__ b_out, float* __restrict__ out)
{
    __shared__ float hrow[HSZ];
    const int n = blockIdx.x;
    const int tid = threadIdx.x;
    for (int k = tid; k < HSZ; k += 256) {
        float v = hfin[n * HSZ + k];
        hrow[k] = v;
        out[NB * ISZ + n * HSZ + k] = v;   // h_final output
    }
    __syncthreads();
    for (int j = tid; j < ISZ; j += 256) {
        float acc = b_out[j];
        #pragma unroll 8
        for (int k = 0; k < HSZ; ++k)
            acc = fmaf(hrow[k], Wt[k * ISZ + j], acc);
        out[n * ISZ + j] = acc;
    }
}

// -------------------------------------------------------------- launch ----
extern "C" void kernel_launch(void* const* d_in, const int* in_sizes, int n_in,
                              void* d_out, int out_size, void* d_ws, size_t ws_size,
                              hipStream_t stream) {
    (void)in_sizes; (void)n_in; (void)out_size; (void)ws_size;
    const float* x     = (const float*)d_in[0];
    const float* h_in  = (const float*)d_in[1];
    const float* W_ih  = (const float*)d_in[2];
    const float* b_ih  = (const float*)d_in[3];
    const float* W_hh  = (const float*)d_in[4];
    const float* b_hh  = (const float*)d_in[5];
    const float* W_out = (const float*)d_in[6];
    const float* b_out = (const float*)d_in[7];
    float* out = (float*)d_out;

    char* ws = (char*)d_ws;
    size_t o = 0;
    u16*    Bhi   = (u16*)(ws + o);    o += (size_t)64 * TILEBYTES;   // 9,437,184
    u16*    Blo   = (u16*)(ws + o);    o += (size_t)64 * TILEBYTES;   // 9,437,184
    float*  Wt    = (float*)(ws + o);  o += (size_t)HSZ * ISZ * 4;    // 2,097,152
    float4* bias4 = (float4*)(ws + o); o += (size_t)HSZ * 16;         //    16,384
    float*  hf    = (float*)(ws + o);  o += (size_t)NB * HSZ * 4;     // 1,048,576
    u16* hb[2]; u16* xb[2];
    for (int b = 0; b < 2; ++b) { hb[b] = (u16*)(ws + o); o += (size_t)NB * HSZ * 2; }
    for (int b = 0; b < 2; ++b) { xb[b] = (u16*)(ws + o); o += (size_t)NB * ISZ * 2; }
    // total ~23.6 MB

    prep_kernel<<<(64 * TILE_U16) / 256, 256, 0, stream>>>(
        W_ih, W_hh, b_ih, b_hh, W_out, Bhi, Blo, Wt, bias4);
    init_kernel<<<(NB * ISZ) / 256, 256, 0, stream>>>(
        x, h_in, xb[0], hf, hb[0]);

    for (int t = 0; t < LSEQ; ++t) {
        const int cur = t & 1, nxt = cur ^ 1;
        gru_step<<<256, 512, LDS_BYTES, stream>>>(
            x, t, Bhi, Blo, bias4,
            xb[cur], xb[nxt],
            hf, hb[cur], hb[nxt]);
    }
    head_kernel<<<NB, 256, 0, stream>>>(hf, Wt, b_out, out);
}